// Round 1
// baseline (158.948 us; speedup 1.0000x reference)
//
#include <hip/hip_runtime.h>

// RGCNDirectional: out = sum_r (A[r] @ (X @ W[r]^T)) / (rowsum(A[r]) + eps)
// X:[4096,128] f32, A:[8,4096,4096] f32 (512MB, HBM-bound), W:[8,128,128] f32.
// Strategy: bf16 MFMA, A read exactly once (norms fused into staging).

#define N_NODES 4096
#define DIM     128
#define NREL    8
#define EPS_F   1e-12f

typedef __attribute__((ext_vector_type(4))) float f32x4;
typedef __attribute__((ext_vector_type(8))) short bf16x8;
typedef __attribute__((ext_vector_type(4))) short s16x4;
typedef __attribute__((ext_vector_type(8))) unsigned short u16x8;

__device__ __forceinline__ unsigned short f2bf(float f) {
  unsigned u = __float_as_uint(f);
  unsigned r = (u + 0x7fffu + ((u >> 16) & 1u)) >> 16;   // RNE
  return (unsigned short)r;
}

__device__ __forceinline__ bf16x8 cvt8(const float* p) {
  f32x4 lo = *reinterpret_cast<const f32x4*>(p);
  f32x4 hi = *reinterpret_cast<const f32x4*>(p + 4);
  bf16x8 o;
#pragma unroll
  for (int j = 0; j < 4; ++j) { o[j] = (short)f2bf(lo[j]); o[j + 4] = (short)f2bf(hi[j]); }
  return o;
}

// ---------------------------------------------------------------------------
// Kernel 1: Ht[r][o][n] = sum_d X[n][d] * W[r][o][d], stored bf16, o-major.
// GEMM: A-op = W[r] (o x d, k-contig rows), B-op = X^T (d x n; X rows are
// k-contig). Both fragments load straight from global (L2-resident), no LDS.
// ---------------------------------------------------------------------------
__global__ __launch_bounds__(256) void h_kernel(const float* __restrict__ X,
                                                const float* __restrict__ W,
                                                short* __restrict__ Ht) {
  const int r  = blockIdx.x >> 5;          // 32 n-tiles of 128
  const int n0 = (blockIdx.x & 31) * 128;
  const int lane = threadIdx.x & 63;
  const int wid  = threadIdx.x >> 6;
  const int wm = wid >> 1, wn = wid & 1;   // 2x2 wave grid, 64x64 per wave
  const int l15 = lane & 15, l4 = lane >> 4;

  const float* Wr = W + (size_t)r * DIM * DIM;
  f32x4 acc[4][4] = {};

#pragma unroll
  for (int ks = 0; ks < 4; ++ks) {         // K = 128 = 4 * 32
    const int k = ks * 32 + l4 * 8;
    bf16x8 a[4], b[4];
#pragma unroll
    for (int mi = 0; mi < 4; ++mi)
      a[mi] = cvt8(Wr + (size_t)(wm * 64 + mi * 16 + l15) * DIM + k);
#pragma unroll
    for (int ni = 0; ni < 4; ++ni)
      b[ni] = cvt8(X + (size_t)(n0 + wn * 64 + ni * 16 + l15) * DIM + k);
#pragma unroll
    for (int mi = 0; mi < 4; ++mi)
#pragma unroll
      for (int ni = 0; ni < 4; ++ni)
        acc[mi][ni] = __builtin_amdgcn_mfma_f32_16x16x32_bf16(a[mi], b[ni], acc[mi][ni], 0, 0, 0);
  }

#pragma unroll
  for (int mi = 0; mi < 4; ++mi)
#pragma unroll
    for (int ni = 0; ni < 4; ++ni)
#pragma unroll
      for (int i = 0; i < 4; ++i) {
        const int o = wm * 64 + mi * 16 + l4 * 4 + i;
        const int n = n0 + wn * 64 + ni * 16 + l15;
        Ht[((size_t)r * DIM + o) * N_NODES + n] = (short)f2bf(acc[mi][ni][i]);
      }
}

// ---------------------------------------------------------------------------
// Kernel 2: main. Per block: relation r, 64 rows of out; K-sweep over 4096.
// Reads A f32 (converted to bf16 in regs), Ht bf16 (L2-resident per XCD).
// Rowsum of A accumulated in f32 during staging (norm fusion).
// LDS double-buffered, next-tile loads issued before compute (T3-lite).
// ---------------------------------------------------------------------------
#define BM 64
#define BK 64
#define NKT (N_NODES / BK)   // 64 iterations

__global__ __launch_bounds__(256, 2) void rgcn_main(const float* __restrict__ A,
                                                    const short* __restrict__ Ht,
                                                    float* __restrict__ out) {
  // XCD-aware swizzle (grid 512 = 8 XCD * 64): XCD x owns relation x entirely,
  // so Ht[r] (1 MB bf16) stays resident in that XCD's L2.
  const int nwg = gridDim.x;
  const int logical = (blockIdx.x & 7) * (nwg >> 3) + (blockIdx.x >> 3);
  const int r  = logical >> 6;       // 64 m-tiles per relation
  const int m0 = (logical & 63) * BM;

  const int tid  = threadIdx.x;
  const int lane = tid & 63;
  const int wid  = tid >> 6;
  const int wm = wid >> 1, wn = wid & 1;   // per-wave: 32 rows x 64 cols
  const int l15 = lane & 15, l4 = lane >> 4;

  // staging maps
  const int ach = tid & 15;   // A float4-chunk within row (64 cols = 16 chunks)
  const int arb = tid >> 4;   // A row base (0..15), 4 passes of 16 rows
  const int hch = tid & 7;    // Ht 16B-chunk within row (64 cols = 8 chunks)
  const int hrb = tid >> 3;   // Ht row base (0..31), 4 passes of 32 rows

  __shared__ short As[2][BM][72];     // +8 pad: 144B row stride -> 2-way (free)
  __shared__ short Hs[2][DIM][72];
  __shared__ float norm_s[BM];

  const float* Ag = A + ((size_t)r * N_NODES + m0) * N_NODES;
  const short* Hg = Ht + (size_t)r * DIM * N_NODES;

  f32x4 aval[4];
  u16x8 hval[4];
  float rowsum[4] = {0.f, 0.f, 0.f, 0.f};
  f32x4 acc[2][4] = {};

  auto load_tile = [&](int kt) {
    const int k0 = kt * BK;
#pragma unroll
    for (int p = 0; p < 4; ++p)
      aval[p] = *reinterpret_cast<const f32x4*>(Ag + (size_t)(arb + 16 * p) * N_NODES + k0 + ach * 4);
#pragma unroll
    for (int q = 0; q < 4; ++q)
      hval[q] = *reinterpret_cast<const u16x8*>(Hg + (size_t)(hrb + 32 * q) * N_NODES + k0 + hch * 8);
  };

  auto store_tile = [&](int buf) {
#pragma unroll
    for (int p = 0; p < 4; ++p) {
      s16x4 b;
#pragma unroll
      for (int j = 0; j < 4; ++j) {
        b[j] = (short)f2bf(aval[p][j]);
        rowsum[p] += aval[p][j];
      }
      *reinterpret_cast<s16x4*>(&As[buf][arb + 16 * p][ach * 4]) = b;
    }
#pragma unroll
    for (int q = 0; q < 4; ++q)
      *reinterpret_cast<u16x8*>(&Hs[buf][hrb + 32 * q][hch * 8]) = hval[q];
  };

  auto compute = [&](int buf) {
#pragma unroll
    for (int ks = 0; ks < 2; ++ks) {
      bf16x8 a[2], h[4];
#pragma unroll
      for (int mi = 0; mi < 2; ++mi)
        a[mi] = *reinterpret_cast<const bf16x8*>(&As[buf][wm * 32 + mi * 16 + l15][ks * 32 + l4 * 8]);
#pragma unroll
      for (int ni = 0; ni < 4; ++ni)
        h[ni] = *reinterpret_cast<const bf16x8*>(&Hs[buf][wn * 64 + ni * 16 + l15][ks * 32 + l4 * 8]);
#pragma unroll
      for (int mi = 0; mi < 2; ++mi)
#pragma unroll
        for (int ni = 0; ni < 4; ++ni)
          acc[mi][ni] = __builtin_amdgcn_mfma_f32_16x16x32_bf16(a[mi], h[ni], acc[mi][ni], 0, 0, 0);
    }
  };

  // prologue
  load_tile(0);
  store_tile(0);
  __syncthreads();

  int cur = 0;
  for (int kt = 0; kt < NKT; ++kt) {
    if (kt + 1 < NKT) load_tile(kt + 1);   // issue next-tile global loads early
    compute(cur);
    if (kt + 1 < NKT) { store_tile(cur ^ 1); cur ^= 1; }
    __syncthreads();
  }

  // norm reduction: 16 chunk-lanes share each (arb, p) row
#pragma unroll
  for (int p = 0; p < 4; ++p) {
    float s = rowsum[p];
    s += __shfl_xor(s, 1);
    s += __shfl_xor(s, 2);
    s += __shfl_xor(s, 4);
    s += __shfl_xor(s, 8);
    if ((lane & 15) == 0) norm_s[arb + 16 * p] = s + EPS_F;
  }
  __syncthreads();

  // epilogue: divide by norm, accumulate across relations via atomics
#pragma unroll
  for (int mi = 0; mi < 2; ++mi)
#pragma unroll
    for (int ni = 0; ni < 4; ++ni)
#pragma unroll
      for (int i = 0; i < 4; ++i) {
        const int row = wm * 32 + mi * 16 + l4 * 4 + i;
        const int col = wn * 64 + ni * 16 + l15;
        const float v = acc[mi][ni][i] / norm_s[row];
        atomicAdd(&out[(size_t)(m0 + row) * DIM + col], v);
      }
}

extern "C" void kernel_launch(void* const* d_in, const int* in_sizes, int n_in,
                              void* d_out, int out_size, void* d_ws, size_t ws_size,
                              hipStream_t stream) {
  const float* X = (const float*)d_in[0];
  const float* A = (const float*)d_in[1];
  const float* W = (const float*)d_in[2];
  float* out = (float*)d_out;
  short* Ht = (short*)d_ws;   // 8 * 128 * 4096 bf16 = 8 MB

  hipMemsetAsync(d_out, 0, (size_t)out_size * sizeof(float), stream);
  hipLaunchKernelGGL(h_kernel, dim3(NREL * (N_NODES / 128)), dim3(256), 0, stream, X, W, Ht);
  hipLaunchKernelGGL(rgcn_main, dim3(NREL * (N_NODES / BM)), dim3(256), 0, stream, A, Ht, out);
}